// Round 1
// baseline (749.598 us; speedup 1.0000x reference)
//
#include <hip/hip_runtime.h>
#include <hip/hip_bf16.h>

#define NN 100000      // nodes
#define NE 1000000     // edges
#define HID 64
#define EMB 30

// ---------------- workspace layout (float offsets) ----------------
// zeroed region (contiguous): den1[N], acc1[N*64], den2[N], acc2[N*30], colsum[32]
#define OFF_DEN1   0
#define OFF_ACC1   (NN)
#define OFF_DEN2   (65*NN)
#define OFF_ACC2   (66*NN)
#define OFF_COLSUM (96*NN)
#define ZERO_COUNT (96*NN + 32)
// non-zeroed scratch:
#define OFF_Z1     (96*NN + 32)
#define OFF_EL1    (160*NN + 32)
#define OFF_ER1    (161*NN + 32)
#define OFF_Z2     (162*NN + 32)
#define OFF_EL2    (192*NN + 32)
#define OFF_ER2    (193*NN + 32)

__global__ void k0_zero(float* __restrict__ p, int n) {
    int i = blockIdx.x * blockDim.x + threadIdx.x;
    int stride = gridDim.x * blockDim.x;
    for (; i < n; i += stride) p[i] = 0.f;
}

// one wave per node: z1[n,j] = sum_k feat[n,k]*W1[k,j] (head 0 cols), el1/er1 dot-reduce
__global__ void k1_node1(const float* __restrict__ feat, const float* __restrict__ W1,
                         const float* __restrict__ al1, const float* __restrict__ ar1,
                         float* __restrict__ z1, float* __restrict__ el1, float* __restrict__ er1) {
    int gid = blockIdx.x * blockDim.x + threadIdx.x;
    int n = gid >> 6;
    int lane = threadIdx.x & 63;
    if (n >= NN) return;
    float f0 = feat[n*3 + 0], f1 = feat[n*3 + 1], f2 = feat[n*3 + 2];
    float z = f0 * W1[lane] + f1 * W1[128 + lane] + f2 * W1[256 + lane];
    z1[n*64 + lane] = z;
    float a = z * al1[lane];
    float b = z * ar1[lane];
    for (int off = 32; off > 0; off >>= 1) {
        a += __shfl_down(a, off);
        b += __shfl_down(b, off);
    }
    if (lane == 0) { el1[n] = a; er1[n] = b; }
}

// one wave per edge: p = exp(leaky(el[src]+er[dst])); den1[dst]+=p; acc1[dst,:]+=p*z1[src,:]
__global__ void k2_agg1(const int* __restrict__ src, const int* __restrict__ dst,
                        const float* __restrict__ el1, const float* __restrict__ er1,
                        const float* __restrict__ z1,
                        float* __restrict__ den1, float* __restrict__ acc1) {
    int gid = blockIdx.x * blockDim.x + threadIdx.x;
    int e = gid >> 6;
    int lane = threadIdx.x & 63;
    if (e >= NE) return;
    int s = src[e], d = dst[e];
    float ee = el1[s] + er1[d];
    ee = (ee >= 0.f) ? ee : 0.2f * ee;
    float p = __expf(ee);
    if (lane == 0) atomicAdd(den1 + d, p);
    atomicAdd(acc1 + d*64 + lane, p * z1[s*64 + lane]);
}

// one thread per node: r1 = relu(acc1/den1 + b1[0]); z2_00 = r1 @ W2[:,0:30]; el2/er2
__global__ void k3_node2(const float* __restrict__ den1, const float* __restrict__ acc1,
                         const float* __restrict__ b1, const float* __restrict__ W2,
                         const float* __restrict__ al2, const float* __restrict__ ar2,
                         float* __restrict__ z2, float* __restrict__ el2, float* __restrict__ er2) {
    int n = blockIdx.x * blockDim.x + threadIdx.x;
    if (n >= NN) return;
    float dn = den1[n];
    float inv = (dn > 0.f) ? 1.f / dn : 0.f;
    float r[64];
#pragma unroll
    for (int k = 0; k < 64; ++k)
        r[k] = fmaxf(acc1[n*64 + k] * inv + b1[k], 0.f);
    float sl = 0.f, sr = 0.f;
    for (int c = 0; c < 30; ++c) {
        float z = 0.f;
#pragma unroll
        for (int k = 0; k < 64; ++k) z += r[k] * W2[k*60 + c];
        z2[n*30 + c] = z;
        sl += z * al2[c];
        sr += z * ar2[c];
    }
    el2[n] = sl;
    er2[n] = sr;
}

// one wave per edge (30 active lanes): layer-2 aggregation, head pair (0,0) only
__global__ void k4_agg2(const int* __restrict__ src, const int* __restrict__ dst,
                        const float* __restrict__ el2, const float* __restrict__ er2,
                        const float* __restrict__ z2,
                        float* __restrict__ den2, float* __restrict__ acc2) {
    int gid = blockIdx.x * blockDim.x + threadIdx.x;
    int e = gid >> 6;
    int lane = threadIdx.x & 63;
    if (e >= NE) return;
    int s = src[e], d = dst[e];
    float ee = el2[s] + er2[d];
    ee = (ee >= 0.f) ? ee : 0.2f * ee;
    float p = __expf(ee);
    if (lane == 0) atomicAdd(den2 + d, p);
    if (lane < 30) atomicAdd(acc2 + d*30 + lane, p * z2[s*30 + lane]);
}

// grid-stride per-thread column sums of out2_00, wave-reduce, atomicAdd colsum[30]
__global__ void k5_colsum(const float* __restrict__ den2, const float* __restrict__ acc2,
                          float* __restrict__ colsum) {
    int tid = blockIdx.x * blockDim.x + threadIdx.x;
    int lane = threadIdx.x & 63;
    int stride = gridDim.x * blockDim.x;
    float r[30];
#pragma unroll
    for (int j = 0; j < 30; ++j) r[j] = 0.f;
    for (int n = tid; n < NN; n += stride) {
        float dn = den2[n];
        float inv = (dn > 0.f) ? 1.f / dn : 0.f;
#pragma unroll
        for (int j = 0; j < 30; ++j) r[j] += acc2[n*30 + j] * inv;
    }
#pragma unroll
    for (int j = 0; j < 30; ++j)
        for (int off = 32; off > 0; off >>= 1) r[j] += __shfl_down(r[j], off);
    if (lane == 0) {
#pragma unroll
        for (int j = 0; j < 30; ++j) atomicAdd(colsum + j, r[j]);
    }
}

// single block: image path (h_i, h_img), a00 = colsum/N + b2[0], concat, log_softmax
__global__ void k6_final(const float* __restrict__ x, const float* __restrict__ vocab,
                         const float* __restrict__ W_lin1, const float* __restrict__ w2,
                         const float* __restrict__ w3, const float* __restrict__ W4,
                         const float* __restrict__ b2, const float* __restrict__ colsum,
                         float* __restrict__ out) {
    __shared__ float sh[256];
    __shared__ float hvec[70];
    int tid = threadIdx.x;
    // h_i[r] = W_lin1[r,:] @ x  -- 8 threads per row
    int r = tid >> 3, sub = tid & 7;
    float part = 0.f;
    if (r < 30) {
        for (int k = sub; k < 512; k += 8) part += W_lin1[r*512 + k] * x[k];
    }
    sh[tid] = part;
    __syncthreads();
    if (tid < 30) {
        float hi = 0.f;
        for (int i = 0; i < 8; ++i) hi += sh[tid*8 + i];
        // h_img[j] = sigmoid( sum_k w3[k] * sigmoid(w2[k]*h_i[j]) )
        float acc = 0.f;
        for (int k = 0; k < 64; ++k) acc += w3[k] / (1.f + __expf(-w2[k] * hi));
        hvec[30 + tid] = 1.f / (1.f + __expf(-acc));
        hvec[tid] = colsum[tid] * (1.0f / (float)NN) + b2[tid];
    }
    if (tid >= 64 && tid < 74) hvec[60 + (tid - 64)] = vocab[tid - 64];
    __syncthreads();
    if (tid == 0) {
        float p0 = 0.f, p1 = 0.f;
        for (int k = 0; k < 70; ++k) {
            p0 += W4[k] * hvec[k];
            p1 += W4[70 + k] * hvec[k];
        }
        float mx = fmaxf(p0, p1);
        float l = logf(__expf(p0 - mx) + __expf(p1 - mx));
        out[0] = p0 - mx - l;
        out[1] = p1 - mx - l;
    }
}

extern "C" void kernel_launch(void* const* d_in, const int* in_sizes, int n_in,
                              void* d_out, int out_size, void* d_ws, size_t ws_size,
                              hipStream_t stream) {
    const float* x      = (const float*)d_in[0];
    const float* feat   = (const float*)d_in[1];
    const float* vocab  = (const float*)d_in[2];
    const int*   src    = (const int*)d_in[3];
    const int*   dst    = (const int*)d_in[4];
    const float* W_lin1 = (const float*)d_in[5];
    const float* w_c2   = (const float*)d_in[6];
    const float* w_c3   = (const float*)d_in[7];
    const float* W_lin4 = (const float*)d_in[8];
    const float* W1     = (const float*)d_in[9];
    const float* al1    = (const float*)d_in[10];
    const float* ar1    = (const float*)d_in[11];
    const float* b1     = (const float*)d_in[12];
    const float* W2     = (const float*)d_in[13];
    const float* al2    = (const float*)d_in[14];
    const float* ar2    = (const float*)d_in[15];
    const float* b2     = (const float*)d_in[16];
    float* out = (float*)d_out;
    float* w = (float*)d_ws;

    float* den1   = w + OFF_DEN1;
    float* acc1   = w + OFF_ACC1;
    float* den2   = w + OFF_DEN2;
    float* acc2   = w + OFF_ACC2;
    float* colsum = w + OFF_COLSUM;
    float* z1     = w + OFF_Z1;
    float* el1    = w + OFF_EL1;
    float* er1    = w + OFF_ER1;
    float* z2     = w + OFF_Z2;
    float* el2    = w + OFF_EL2;
    float* er2    = w + OFF_ER2;

    // zero accumulators (ws is poisoned 0xAA before every call)
    k0_zero<<<2048, 256, 0, stream>>>(w, ZERO_COUNT);

    // layer 1 node projections
    k1_node1<<<(NN*64 + 255) / 256, 256, 0, stream>>>(feat, W1, al1, ar1, z1, el1, er1);

    // layer 1 edge softmax + weighted aggregation (one wave per edge)
    k2_agg1<<<(NE*64) / 256, 256, 0, stream>>>(src, dst, el1, er1, z1, den1, acc1);

    // layer 1 finalize + layer 2 node projections
    k3_node2<<<(NN + 255) / 256, 256, 0, stream>>>(den1, acc1, b1, W2, al2, ar2, z2, el2, er2);

    // layer 2 edge softmax + weighted aggregation
    k4_agg2<<<(NE*64) / 256, 256, 0, stream>>>(src, dst, el2, er2, z2, den2, acc2);

    // column means over nodes
    k5_colsum<<<104, 256, 0, stream>>>(den2, acc2, colsum);

    // epilogue: image path + concat + log_softmax
    k6_final<<<1, 256, 0, stream>>>(x, vocab, W_lin1, w_c2, w_c3, W_lin4, b2, colsum, out);
}

// Round 2
// 421.613 us; speedup vs baseline: 1.7779x; 1.7779x over previous
//
#include <hip/hip_runtime.h>
#include <hip/hip_bf16.h>

#define NN 100000      // nodes
#define NE 1000000     // edges

// ---------------- workspace layout (float offsets) ----------------
// zeroed region: accA[N*4] = per-node {sum p*f0, p*f1, p*f2, den1}; den2[N]
#define OFF_ACCA   0
#define OFF_DEN2   (4*NN)
#define ZERO_COUNT (5*NN)
// non-zeroed scratch:
#define OFF_P      (5*NN)              // E
#define OFF_EL2    (5*NN + NE)         // N
#define OFF_ER2    (6*NN + NE)         // N
#define OFF_Z2     (7*NN + NE)         // 32*N (rows padded to 32, cols 30,31 = 0)
#define OFF_CLCR   (39*NN + NE)        // 8: cl[3] @0..2, cr[3] @4..6
#define OFF_PART   (39*NN + NE + 8)    // 256*32 block partials

// zero accumulators + compute cl[k]=W1[k,:64]@al1, cr[k]=W1[k,:64]@ar1 (block 0, wave 0)
__global__ void k0_zero_prep(float* __restrict__ w, const float* __restrict__ W1,
                             const float* __restrict__ al1, const float* __restrict__ ar1,
                             float* __restrict__ clcr) {
    int i = blockIdx.x * blockDim.x + threadIdx.x;
    if (i < ZERO_COUNT) w[i] = 0.f;
    if (blockIdx.x == 0 && threadIdx.x < 64) {
        int j = threadIdx.x;
        float a = al1[j], r = ar1[j];
#pragma unroll
        for (int k = 0; k < 3; ++k) {
            float wv = W1[k*128 + j];
            float vl = wv * a, vr = wv * r;
            for (int off = 32; off > 0; off >>= 1) {
                vl += __shfl_down(vl, off);
                vr += __shfl_down(vr, off);
            }
            if (j == 0) { clcr[k] = vl; clcr[4 + k] = vr; }
        }
    }
}

// one thread per edge: p = exp(leaky(feat[s]·cl + feat[d]·cr)); 4 scalar atomics
__global__ void k2_agg1(const int* __restrict__ src, const int* __restrict__ dst,
                        const float* __restrict__ feat, const float* __restrict__ clcr,
                        float* __restrict__ accA) {
    int e = blockIdx.x * blockDim.x + threadIdx.x;
    if (e >= NE) return;
    int s = src[e], d = dst[e];
    float fs0 = feat[s*3], fs1 = feat[s*3+1], fs2 = feat[s*3+2];
    float fd0 = feat[d*3], fd1 = feat[d*3+1], fd2 = feat[d*3+2];
    float ee = fs0*clcr[0] + fs1*clcr[1] + fs2*clcr[2]
             + fd0*clcr[4] + fd1*clcr[5] + fd2*clcr[6];
    ee = (ee >= 0.f) ? ee : 0.2f * ee;
    float p = __expf(ee);
    atomicAdd(accA + d*4 + 0, p * fs0);
    atomicAdd(accA + d*4 + 1, p * fs1);
    atomicAdd(accA + d*4 + 2, p * fs2);
    atomicAdd(accA + d*4 + 3, p);
}

// one thread per node: expand rank-3 agg -> r1 = relu(.+b1), z2 = r1@W2[:,:30], el2/er2
__global__ void k3_node2(const float* __restrict__ accA, const float* __restrict__ W1,
                         const float* __restrict__ b1, const float* __restrict__ W2,
                         const float* __restrict__ al2, const float* __restrict__ ar2,
                         float* __restrict__ z2, float* __restrict__ el2, float* __restrict__ er2) {
    int n = blockIdx.x * blockDim.x + threadIdx.x;
    if (n >= NN) return;
    float den = accA[n*4 + 3];
    float inv = (den > 0.f) ? 1.f / den : 0.f;
    float a0 = accA[n*4 + 0] * inv;
    float a1 = accA[n*4 + 1] * inv;
    float a2 = accA[n*4 + 2] * inv;
    float r[64];
#pragma unroll
    for (int j = 0; j < 64; ++j) {
        float v = a0 * W1[j] + a1 * W1[128 + j] + a2 * W1[256 + j] + b1[j];
        r[j] = fmaxf(v, 0.f);
    }
    float sl = 0.f, sr = 0.f;
    for (int c = 0; c < 30; ++c) {
        float z = 0.f;
#pragma unroll
        for (int j = 0; j < 64; ++j) z += r[j] * W2[j*60 + c];
        z2[n*32 + c] = z;
        sl += z * al2[c];
        sr += z * ar2[c];
    }
    z2[n*32 + 30] = 0.f;
    z2[n*32 + 31] = 0.f;
    el2[n] = sl;
    er2[n] = sr;
}

// one thread per edge: p2 = exp(leaky(el2[s]+er2[d])), cache it, den2[d] += p2
__global__ void k4a_den2(const int* __restrict__ src, const int* __restrict__ dst,
                         const float* __restrict__ el2, const float* __restrict__ er2,
                         float* __restrict__ pbuf, float* __restrict__ den2) {
    int e = blockIdx.x * blockDim.x + threadIdx.x;
    if (e >= NE) return;
    int s = src[e], d = dst[e];
    float ee = el2[s] + er2[d];
    ee = (ee >= 0.f) ? ee : 0.2f * ee;
    float p = __expf(ee);
    pbuf[e] = p;
    atomicAdd(den2 + d, p);
}

// flat edge reduction: colsum[j] = sum_e (p_e/den2[d_e]) * z2[s_e, j]; per-block partials
__global__ void k4b_colsum(const int* __restrict__ src, const int* __restrict__ dst,
                           const float* __restrict__ pbuf, const float* __restrict__ den2,
                           const float* __restrict__ z2, float* __restrict__ part) {
    __shared__ float sh[4][32];
    int tid = threadIdx.x;
    int lane = tid & 63, wv = tid >> 6;
    float r[32];
#pragma unroll
    for (int q = 0; q < 32; ++q) r[q] = 0.f;
    for (int e = blockIdx.x * 256 + tid; e < NE; e += 256 * 256) {
        int s = src[e], d = dst[e];
        float alpha = pbuf[e] / den2[d];
        const float4* zr = (const float4*)(z2 + (size_t)s * 32);
#pragma unroll
        for (int q = 0; q < 8; ++q) {
            float4 v = zr[q];
            r[4*q + 0] += alpha * v.x;
            r[4*q + 1] += alpha * v.y;
            r[4*q + 2] += alpha * v.z;
            r[4*q + 3] += alpha * v.w;
        }
    }
#pragma unroll
    for (int q = 0; q < 32; ++q)
        for (int off = 32; off > 0; off >>= 1) r[q] += __shfl_down(r[q], off);
    if (lane == 0) {
#pragma unroll
        for (int q = 0; q < 32; ++q) sh[wv][q] = r[q];
    }
    __syncthreads();
    if (tid < 32)
        part[blockIdx.x * 32 + tid] = sh[0][tid] + sh[1][tid] + sh[2][tid] + sh[3][tid];
}

// single block: image path, sum partials, a00 = colsum/N + b2[0], concat, log_softmax
__global__ void k6_final(const float* __restrict__ x, const float* __restrict__ vocab,
                         const float* __restrict__ W_lin1, const float* __restrict__ w2,
                         const float* __restrict__ w3, const float* __restrict__ W4,
                         const float* __restrict__ b2, const float* __restrict__ part,
                         float* __restrict__ out) {
    __shared__ float sh[256];
    __shared__ float hvec[70];
    int tid = threadIdx.x;
    int r = tid >> 3, sub = tid & 7;
    float pt = 0.f;
    if (r < 30) {
        for (int k = sub; k < 512; k += 8) pt += W_lin1[r*512 + k] * x[k];
    }
    sh[tid] = pt;
    __syncthreads();
    if (tid < 30) {
        float hi = 0.f;
        for (int i = 0; i < 8; ++i) hi += sh[tid*8 + i];
        float acc = 0.f;
        for (int k = 0; k < 64; ++k) acc += w3[k] / (1.f + __expf(-w2[k] * hi));
        hvec[30 + tid] = 1.f / (1.f + __expf(-acc));
        float cs = 0.f;
        for (int b = 0; b < 256; ++b) cs += part[b*32 + tid];
        hvec[tid] = cs * (1.0f / (float)NN) + b2[tid];
    }
    if (tid >= 64 && tid < 74) hvec[60 + (tid - 64)] = vocab[tid - 64];
    __syncthreads();
    if (tid == 0) {
        float p0 = 0.f, p1 = 0.f;
        for (int k = 0; k < 70; ++k) {
            p0 += W4[k] * hvec[k];
            p1 += W4[70 + k] * hvec[k];
        }
        float mx = fmaxf(p0, p1);
        float l = logf(__expf(p0 - mx) + __expf(p1 - mx));
        out[0] = p0 - mx - l;
        out[1] = p1 - mx - l;
    }
}

extern "C" void kernel_launch(void* const* d_in, const int* in_sizes, int n_in,
                              void* d_out, int out_size, void* d_ws, size_t ws_size,
                              hipStream_t stream) {
    const float* x      = (const float*)d_in[0];
    const float* feat   = (const float*)d_in[1];
    const float* vocab  = (const float*)d_in[2];
    const int*   src    = (const int*)d_in[3];
    const int*   dst    = (const int*)d_in[4];
    const float* W_lin1 = (const float*)d_in[5];
    const float* w_c2   = (const float*)d_in[6];
    const float* w_c3   = (const float*)d_in[7];
    const float* W_lin4 = (const float*)d_in[8];
    const float* W1     = (const float*)d_in[9];
    const float* al1    = (const float*)d_in[10];
    const float* ar1    = (const float*)d_in[11];
    const float* b1     = (const float*)d_in[12];
    const float* W2     = (const float*)d_in[13];
    const float* al2    = (const float*)d_in[14];
    const float* ar2    = (const float*)d_in[15];
    const float* b2     = (const float*)d_in[16];
    float* out = (float*)d_out;
    float* w = (float*)d_ws;

    float* accA = w + OFF_ACCA;
    float* den2 = w + OFF_DEN2;
    float* pbuf = w + OFF_P;
    float* el2  = w + OFF_EL2;
    float* er2  = w + OFF_ER2;
    float* z2   = w + OFF_Z2;
    float* clcr = w + OFF_CLCR;
    float* part = w + OFF_PART;

    // zero accumulators + attn-coeff prep
    k0_zero_prep<<<(ZERO_COUNT + 255) / 256, 256, 0, stream>>>(w, W1, al1, ar1, clcr);

    // layer 1: rank-3 edge aggregation (4 scalar atomics per edge)
    k2_agg1<<<(NE + 255) / 256, 256, 0, stream>>>(src, dst, feat, clcr, accA);

    // layer 1 finalize + layer 2 node projections
    k3_node2<<<(NN + 255) / 256, 256, 0, stream>>>(accA, W1, b1, W2, al2, ar2, z2, el2, er2);

    // layer 2 pass A: denominators + cached p
    k4a_den2<<<(NE + 255) / 256, 256, 0, stream>>>(src, dst, el2, er2, pbuf, den2);

    // layer 2 pass B: flat edge reduction into 256 block partials
    k4b_colsum<<<256, 256, 0, stream>>>(src, dst, pbuf, den2, z2, part);

    // epilogue
    k6_final<<<1, 256, 0, stream>>>(x, vocab, W_lin1, w_c2, w_c3, W_lin4, b2, part, out);
}